// Round 8
// baseline (783.691 us; speedup 1.0000x reference)
//
#include <hip/hip_runtime.h>

typedef _Float16 f16x8 __attribute__((ext_vector_type(8)));
typedef _Float16 f16x4 __attribute__((ext_vector_type(4)));
typedef float f32x4 __attribute__((ext_vector_type(4)));

static __device__ __forceinline__ f32x4 MFMA(f16x8 a, f16x8 b, f32x4 c) {
  return __builtin_amdgcn_mfma_f32_16x16x32_f16(a, b, c, 0, 0, 0);
}

// Barrier that drains LDS ops (visibility) but leaves global loads in flight:
// lgkmcnt(0) + raw s_barrier (+sched_barrier: rule "no MFMA hoist past asm wait").
#define BAR()                                          \
  do {                                                 \
    asm volatile("s_waitcnt lgkmcnt(0)" ::: "memory"); \
    __builtin_amdgcn_s_barrier();                      \
    __builtin_amdgcn_sched_barrier(0);                 \
  } while (0)

// ---- weight conversion pre-kernel ------------------------------------------
// ws layout:
//   Wb   : 3 x [224][256] f16  (Wq,Wk,Wv; rows >=200 zero)      @ 0       (344064 B)
//   Wcb  : [224][1024] f16     (conv_w flat; rows >=200 zero)   @ 344064  (458752 B)
//   biasp: 3 x [224] f32       (bq,bk,bv padded w/ zeros)       @ 802816  (2688 B)
//   Qg   : [4096][64][224] f16                                  @ 805888
//   Kg   : [4096][64][224] f16                                  @ 805888+117440512
//   Vtg  : [4096][224][64] f16                                  @ 805888+234881024
__global__ void wcvt(const float* __restrict__ Wq, const float* __restrict__ Wk,
                     const float* __restrict__ Wv, const float* __restrict__ cw,
                     const float* __restrict__ bq, const float* __restrict__ bk,
                     const float* __restrict__ bv,
                     _Float16* __restrict__ Wb,
                     _Float16* __restrict__ Wcb,
                     float* __restrict__ biasp) {
  int gt = blockIdx.x * blockDim.x + threadIdx.x;
  int gs = gridDim.x * blockDim.x;
  const int WN = 224 * 256;
  for (int i = gt; i < WN; i += gs) {
    int n = i >> 8;
    Wb[i]          = (n < 200) ? (_Float16)Wq[i] : (_Float16)0.f;
    Wb[WN + i]     = (n < 200) ? (_Float16)Wk[i] : (_Float16)0.f;
    Wb[2 * WN + i] = (n < 200) ? (_Float16)Wv[i] : (_Float16)0.f;
  }
  for (int i = gt; i < 224 * 1024; i += gs) {
    int o = i >> 10;
    Wcb[i] = (o < 200) ? (_Float16)cw[i] : (_Float16)0.f;
  }
  for (int i = gt; i < 224; i += gs) {
    biasp[i]       = (i < 200) ? bq[i] : 0.f;
    biasp[224 + i] = (i < 200) ? bk[i] : 0.f;
    biasp[448 + i] = (i < 200) ? bv[i] : 0.f;
  }
}

// ---- K1 v2: projections + conv, 2 batches per block, 2 blocks/CU ------------
__global__ __launch_bounds__(512, 4) void k1_proj_conv(
    const float* __restrict__ x, const _Float16* __restrict__ Wb,
    const _Float16* __restrict__ Wcb, const float* __restrict__ biasp,
    const float* __restrict__ convb,
    _Float16* __restrict__ Qg, _Float16* __restrict__ Kg,
    _Float16* __restrict__ Vtg, float* __restrict__ out) {
  extern __shared__ char smem[];
  _Float16* Xl = (_Float16*)smem;  // 2 x [64][264]
  const int tid = threadIdx.x, lane = tid & 63, wave = tid >> 6;
  const int li = lane & 15, g = lane >> 4;
  const int b0 = blockIdx.x * 2;

  const float* xb = x + (size_t)b0 * 16384;
#pragma unroll
  for (int j = 0; j < 16; j++) {
    int f = tid + 512 * j;
    float4 v = ((const float4*)xb)[f];
    int bt = f >> 12, rem = f & 4095, l = rem >> 6, c4 = rem & 63;
    f16x4 h;
    h.x = (_Float16)v.x; h.y = (_Float16)v.y;
    h.z = (_Float16)v.z; h.w = (_Float16)v.w;
    *(f16x4*)(Xl + bt * 16896 + l * 264 + c4 * 4) = h;
  }
  __syncthreads();

#pragma unroll 1
  for (int i = 0; i < 7; i++) {
    int u = wave + 8 * i;
    if (u < 28) {
      // ---- Q/K unit, swapped operands: D[n][l] ----
      int p = u / 14, nt = u % 14;
      const _Float16* wrow = Wb + p * 57344 + (nt * 16 + li) * 256 + 8 * g;
      f32x4 acc[2][4] = {};
#pragma unroll
      for (int kk = 0; kk < 8; kk++) {
        f16x8 aw = *(const f16x8*)(wrow + 32 * kk);
#pragma unroll
        for (int bt = 0; bt < 2; bt++)
#pragma unroll
          for (int mt = 0; mt < 4; mt++) {
            f16x8 bx = *(const f16x8*)(Xl + bt * 16896 + (mt * 16 + li) * 264 + 32 * kk + 8 * g);
            acc[bt][mt] = MFMA(aw, bx, acc[bt][mt]);
          }
      }
      float4 b4 = *(const float4*)(biasp + p * 224 + nt * 16 + 4 * g);
      _Float16* dst0 = (p == 0) ? Qg : Kg;
#pragma unroll
      for (int bt = 0; bt < 2; bt++) {
        _Float16* db = dst0 + (size_t)(b0 + bt) * 14336;
#pragma unroll
        for (int mt = 0; mt < 4; mt++) {
          f16x4 hv;
          {
            float v0 = acc[bt][mt][0] + b4.x; hv[0] = (_Float16)(v0 > 0.f ? v0 : 0.f);
            float v1 = acc[bt][mt][1] + b4.y; hv[1] = (_Float16)(v1 > 0.f ? v1 : 0.f);
            float v2 = acc[bt][mt][2] + b4.z; hv[2] = (_Float16)(v2 > 0.f ? v2 : 0.f);
            float v3 = acc[bt][mt][3] + b4.w; hv[3] = (_Float16)(v3 > 0.f ? v3 : 0.f);
          }
          *(f16x4*)(db + (mt * 16 + li) * 224 + nt * 16 + 4 * g) = hv;
        }
      }
    } else if (u < 42) {
      // ---- V unit, normal operands: D[l][h]; store transposed [h][l] ----
      int nt = u - 28;
      const _Float16* wrow = Wb + 2 * 57344 + (nt * 16 + li) * 256 + 8 * g;
      f32x4 acc[2][4] = {};
#pragma unroll
      for (int kk = 0; kk < 8; kk++) {
        f16x8 bw = *(const f16x8*)(wrow + 32 * kk);
#pragma unroll
        for (int bt = 0; bt < 2; bt++)
#pragma unroll
          for (int mt = 0; mt < 4; mt++) {
            f16x8 ax = *(const f16x8*)(Xl + bt * 16896 + (mt * 16 + li) * 264 + 32 * kk + 8 * g);
            acc[bt][mt] = MFMA(ax, bw, acc[bt][mt]);
          }
      }
      float bias = biasp[448 + nt * 16 + li];
#pragma unroll
      for (int bt = 0; bt < 2; bt++) {
        _Float16* db = Vtg + (size_t)(b0 + bt) * 14336;
#pragma unroll
        for (int mt = 0; mt < 4; mt++) {
          f16x4 hv;
#pragma unroll
          for (int r = 0; r < 4; r++) {
            float v = acc[bt][mt][r] + bias;
            hv[r] = (_Float16)(v > 0.f ? v : 0.f);
          }
          *(f16x4*)(db + (nt * 16 + li) * 64 + mt * 16 + 4 * g) = hv;
        }
      }
    } else {
      // ---- conv unit ----
      int nt = u - 42, o = nt * 16 + li;
      const _Float16* wrow = Wcb + o * 1024 + 8 * g;
      f32x4 acc[2] = {};
#pragma unroll 4
      for (int kk = 0; kk < 32; kk++) {
        f16x8 bf = *(const f16x8*)(wrow + 32 * kk);
        int i1 = kk * 8 + 2 * g;
        int i2 = i1 + 1;
#pragma unroll
        for (int bt = 0; bt < 2; bt++) {
          const _Float16* xt = Xl + bt * 16896;
          union { f16x4 h[2]; f16x8 v; } af;
          af.h[0] = *(const f16x4*)(xt + (i1 >> 2) * 264 + ((i1 & 3) << 6) + 4 * li);
          af.h[1] = *(const f16x4*)(xt + (i2 >> 2) * 264 + ((i2 & 3) << 6) + 4 * li);
          acc[bt] = MFMA(af.v, bf, acc[bt]);
        }
      }
      if (o < 200) {
        float cb = convb[o];
#pragma unroll
        for (int bt = 0; bt < 2; bt++) {
          float4 vo;
          vo.x = acc[bt][0] + cb; vo.y = acc[bt][1] + cb;
          vo.z = acc[bt][2] + cb; vo.w = acc[bt][3] + cb;
          *(float4*)(out + (size_t)(b0 + bt) * 3200 + o * 16 + 4 * g) = vo;
        }
      }
    }
  }
}

// ---- K3 v3: persistent grid-stride attention with cross-batch prefetch ------
// LDS map (bytes):
//   Ks  [64][228] f16 @ 0       (29184)   overlay: Vt [224][64] swz (28672)
//   Sb  [64][72]  f16 @ 29184   (9216)
//   part[2][4][64] f32 @ 38400  (2048)    ((m,s) per wave per column)
//   Po  [200][17] f32 @ 40448   (13600)
// total 54048 -> 3 blocks/CU (162144 <= 163840)
#define K3_LDS 54048
#define K3_GRID 768
__global__ __launch_bounds__(256, 3) void k3_attn(
    const _Float16* __restrict__ Qg, const _Float16* __restrict__ Kg,
    const _Float16* __restrict__ Vtg, float* __restrict__ out) {
  extern __shared__ char smem[];
  _Float16* Ks   = (_Float16*)smem;            // [64][228]
  _Float16* Vt   = (_Float16*)smem;            // [224][64] swizzled (overlay)
  _Float16* Sb   = (_Float16*)(smem + 29184);  // [64][72]
  float*    part = (float*)(smem + 38400);     // [2][4][64]
  float*    Po   = (float*)(smem + 40448);     // [200][17]

  const int tid = threadIdx.x, lane = tid & 63, wave = tid >> 6;
  const int li = lane & 15, g = lane >> 4;
  const int mt = wave;

  // zero Po once (entries c*17+16 are never touched afterwards)
  for (int i = tid; i < 3400; i += 256) Po[i] = 0.f;

  // cold-start loads for the first batch
  int b = blockIdx.x;
  size_t bb = (size_t)b * 14336;
  f16x8 kreg[7], vreg[7], qreg[7];
#pragma unroll
  for (int i = 0; i < 7; i++)
    kreg[i] = *(const f16x8*)(Kg + bb + (tid + 256 * i) * 8);
#pragma unroll
  for (int i = 0; i < 7; i++)
    vreg[i] = *(const f16x8*)(Vtg + bb + (tid + 256 * i) * 8);
#pragma unroll
  for (int kk = 0; kk < 7; kk++)
    qreg[kk] = *(const f16x8*)(Qg + bb + (mt * 16 + li) * 224 + kk * 32 + 8 * g);

#pragma unroll 1
  for (; b < 4096; b += K3_GRID) {
    const size_t bbn = (size_t)(b + K3_GRID) * 14336;
    const bool pf = (b + K3_GRID) < 4096;

    // ---- write Ks from kreg, then prefetch next K ----
#pragma unroll
    for (int i = 0; i < 7; i++) {
      int j = tid + 256 * i;
      *(f16x8*)(Ks + (j / 28) * 228 + (j % 28) * 8) = kreg[i];
    }
    if (pf) {
#pragma unroll
      for (int i = 0; i < 7; i++)
        kreg[i] = *(const f16x8*)(Kg + bbn + (tid + 256 * i) * 8);
    }
    BAR();  // B1: Ks visible (prev iteration's Po-read/PV synced at B5/B6)

    // ---- scores; then prefetch next Q ----
    f32x4 sacc[4] = {};
#pragma unroll
    for (int kk = 0; kk < 7; kk++) {
#pragma unroll
      for (int nt = 0; nt < 4; nt++) {
        f16x8 kb = *(const f16x8*)(Ks + (nt * 16 + li) * 228 + kk * 32 + 8 * g);
        sacc[nt] = MFMA(qreg[kk], kb, sacc[nt]);
      }
    }
    if (pf) {
#pragma unroll
      for (int kk = 0; kk < 7; kk++)
        qreg[kk] = *(const f16x8*)(Qg + bbn + (mt * 16 + li) * 224 + kk * 32 + 8 * g);
    }
    BAR();  // B2: all Ks reads retired -> Vt overlay writable

    // ---- Vt write (swizzled) from vreg, then prefetch next V ----
#pragma unroll
    for (int i = 0; i < 7; i++) {
      int j = tid + 256 * i;
      int h = j >> 3, c = j & 7;
      *(f16x8*)(Vt + h * 64 + ((c ^ (h & 7)) << 3)) = vreg[i];
    }
    if (pf) {
#pragma unroll
      for (int i = 0; i < 7; i++)
        vreg[i] = *(const f16x8*)(Vtg + bbn + (tid + 256 * i) * 8);
    }

    // ---- softmax phase A: per-wave (m,s) partials, exp in place ----
    float mw[4];
#pragma unroll
    for (int nt = 0; nt < 4; nt++) {
      float m0 = fmaxf(fmaxf(sacc[nt][0], sacc[nt][1]),
                       fmaxf(sacc[nt][2], sacc[nt][3]));
      m0 = fmaxf(m0, __shfl_xor(m0, 16));
      m0 = fmaxf(m0, __shfl_xor(m0, 32));
      mw[nt] = m0;
#pragma unroll
      for (int r = 0; r < 4; r++) sacc[nt][r] = __expf(sacc[nt][r] - m0);
      float s0 = sacc[nt][0] + sacc[nt][1] + sacc[nt][2] + sacc[nt][3];
      s0 += __shfl_xor(s0, 16);
      s0 += __shfl_xor(s0, 32);
      if (g == 0) {
        part[wave * 64 + nt * 16 + li] = m0;
        part[256 + wave * 64 + nt * 16 + li] = s0;
      }
    }
    BAR();  // B3: part + Vt visible

    // ---- softmax phase B: merge partials, write Sb ----
#pragma unroll
    for (int nt = 0; nt < 4; nt++) {
      int col = nt * 16 + li;
      float m0 = part[col], m1 = part[64 + col];
      float m2 = part[128 + col], m3 = part[192 + col];
      float M = fmaxf(fmaxf(m0, m1), fmaxf(m2, m3));
      float S = part[256 + col] * __expf(m0 - M) +
                part[320 + col] * __expf(m1 - M) +
                part[384 + col] * __expf(m2 - M) +
                part[448 + col] * __expf(m3 - M);
      float scale = __expf(mw[nt] - M) / S;
#pragma unroll
      for (int r = 0; r < 4; r++)
        Sb[(mt * 16 + 4 * g + r) * 72 + col] = (_Float16)(sacc[nt][r] * scale);
    }
    BAR();  // B4: Sb visible

    // ---- PV + pooled LDS-atomic accumulation ----
    f16x8 pa[2][4];
#pragma unroll
    for (int kk = 0; kk < 2; kk++)
#pragma unroll
      for (int m2 = 0; m2 < 4; m2++)
        pa[kk][m2] = *(const f16x8*)(Sb + (m2 * 16 + li) * 72 + kk * 32 + 8 * g);

#pragma unroll 1
    for (int ntl = wave; ntl < 14; ntl += 4) {
      int h = ntl * 16 + li;
      f16x8 vb[2];
#pragma unroll
      for (int kk = 0; kk < 2; kk++) {
        int cm = 4 * kk + g;
        vb[kk] = *(const f16x8*)(Vt + h * 64 + ((cm ^ (h & 7)) << 3));
      }
      f32x4 pacc[4] = {};
#pragma unroll
      for (int kk = 0; kk < 2; kk++)
#pragma unroll
        for (int m2 = 0; m2 < 4; m2++)
          pacc[m2] = MFMA(pa[kk][m2], vb[kk], pacc[m2]);
      if (h < 200) {
#pragma unroll
        for (int m2 = 0; m2 < 4; m2++)
#pragma unroll
          for (int r = 0; r < 4; r++) {
            int l = m2 * 16 + 4 * g + r;
            int f = l * 200 + h;
            atomicAdd(&Po[(f >> 6) * 17 + (f & 15)], 0.25f * pacc[m2][r]);
          }
      }
    }
    BAR();  // B5: Po atomics done

    // ---- out += Po; re-zero Po for next batch ----
    {
      float* ob = out + (size_t)b * 3200;
#pragma unroll 1
      for (int t = tid; t < 3200; t += 256) {
        int idx = (t >> 4) * 17 + (t & 15);
        float v = Po[idx];
        Po[idx] = 0.f;
        ob[t] += v;
      }
    }
    BAR();  // B6: Po reads/zeroing done before next batch's atomics
  }
}

// ---- fallback: round-2 fused kernel (known-good 533us), used if ws too small
#define FB_LDS 151296
__global__ __launch_bounds__(512, 2) void fused_fallback(
    const float* __restrict__ x, const _Float16* __restrict__ Wb,
    const _Float16* __restrict__ Wcb, const float* __restrict__ biasp,
    const float* __restrict__ convb, float* __restrict__ out) {
  extern __shared__ char smem[];
  _Float16* Xl = (_Float16*)smem;            // [64][264]
  _Float16* Qs = (_Float16*)(smem + 33792);  // [64][232]
  _Float16* Ks = (_Float16*)(smem + 63488);  // [64][232]
  _Float16* Vt = (_Float16*)(smem + 93184);  // [224][72]
  float* Sf    = (float*)(smem + 125440);    // [64][65]
  _Float16* Sb = (_Float16*)(smem + 142080); // [64][72]
  float* SA    = (float*)(smem + 33792);     // [64][228]
  float* Cv    = (float*)(smem + 125440);    // [16][226]

  const int b = blockIdx.x;
  const int tid = threadIdx.x;
  const int lane = tid & 63;
  const int wave = tid >> 6;
  const int li = lane & 15;
  const int g = lane >> 4;

  const float* xb = x + (size_t)b * 16384;
  for (int i = tid; i < 4096; i += 512) {
    float4 v = ((const float4*)xb)[i];
    int e = i * 4;
    int l = e >> 8, d = e & 255;
    f16x4 h;
    h.x = (_Float16)v.x; h.y = (_Float16)v.y;
    h.z = (_Float16)v.z; h.w = (_Float16)v.w;
    *(f16x4*)(Xl + l * 264 + d) = h;
  }
  __syncthreads();

  for (int u = wave; u < 42; u += 8) {
    int p = u / 14, nt = u % 14;
    int n = nt * 16 + li;
    const _Float16* wrow = Wb + p * 57344 + n * 256 + 8 * g;
    f16x8 bfr[8];
#pragma unroll
    for (int kk = 0; kk < 8; kk++) bfr[kk] = *(const f16x8*)(wrow + kk * 32);
    float bias = biasp[p * 224 + n];
    for (int m = 0; m < 4; m++) {
      f32x4 acc = {0.f, 0.f, 0.f, 0.f};
      const _Float16* arow = Xl + (m * 16 + li) * 264 + 8 * g;
#pragma unroll
      for (int kk = 0; kk < 8; kk++) acc = MFMA(*(const f16x8*)(arow + kk * 32), bfr[kk], acc);
#pragma unroll
      for (int r = 0; r < 4; r++) {
        int row = m * 16 + 4 * g + r;
        float v = acc[r] + bias;
        v = v > 0.f ? v : 0.f;
        _Float16 hv = (_Float16)v;
        if (p == 0) Qs[row * 232 + n] = hv;
        else if (p == 1) Ks[row * 232 + n] = hv;
        else Vt[n * 72 + row] = hv;
      }
    }
  }
  __syncthreads();

  for (int t = wave * 2; t < wave * 2 + 2; t++) {
    int mt = t >> 2, nt = t & 3;
    f32x4 acc = {0.f, 0.f, 0.f, 0.f};
    const _Float16* qrow = Qs + (mt * 16 + li) * 232 + 8 * g;
    const _Float16* krow = Ks + (nt * 16 + li) * 232 + 8 * g;
#pragma unroll
    for (int kk = 0; kk < 7; kk++)
      acc = MFMA(*(const f16x8*)(qrow + kk * 32), *(const f16x8*)(krow + kk * 32), acc);
#pragma unroll
    for (int r = 0; r < 4; r++)
      Sf[(mt * 16 + 4 * g + r) * 65 + nt * 16 + li] = acc[r];
  }
  __syncthreads();

  {
    int m = tid >> 3, r = tid & 7;
    float vals[8];
    float mx = -1e30f;
#pragma unroll
    for (int i = 0; i < 8; i++) {
      float v = Sf[(r + 8 * i) * 65 + m];
      vals[i] = v;
      mx = fmaxf(mx, v);
    }
    mx = fmaxf(mx, __shfl_xor(mx, 1));
    mx = fmaxf(mx, __shfl_xor(mx, 2));
    mx = fmaxf(mx, __shfl_xor(mx, 4));
    float s = 0.f;
#pragma unroll
    for (int i = 0; i < 8; i++) { vals[i] = __expf(vals[i] - mx); s += vals[i]; }
    s += __shfl_xor(s, 1);
    s += __shfl_xor(s, 2);
    s += __shfl_xor(s, 4);
    float inv = 1.0f / s;
#pragma unroll
    for (int i = 0; i < 8; i++)
      Sb[(r + 8 * i) * 72 + m] = (_Float16)(vals[i] * inv);
  }
  __syncthreads();

  for (int nt = wave; nt < 14; nt += 8) {
    int o = nt * 16 + li;
    const _Float16* wrow = Wcb + o * 1024 + 8 * g;
    f32x4 acc = {0.f, 0.f, 0.f, 0.f};
#pragma unroll 4
    for (int kk = 0; kk < 32; kk++) {
      int i1 = kk * 8 + 2 * g;
      int i2 = i1 + 1;
      union { f16x4 h[2]; f16x8 v; } af;
      af.h[0] = *(const f16x4*)(Xl + (i1 >> 2) * 264 + ((i1 & 3) << 6) + 4 * li);
      af.h[1] = *(const f16x4*)(Xl + (i2 >> 2) * 264 + ((i2 & 3) << 6) + 4 * li);
      acc = MFMA(af.v, *(const f16x8*)(wrow + 32 * kk), acc);
    }
#pragma unroll
    for (int r = 0; r < 4; r++) Cv[(4 * g + r) * 226 + o] = acc[r];
  }

  for (int t = wave; t < 56; t += 8) {
    int mt = t / 14, nt = t % 14;
    f32x4 acc = {0.f, 0.f, 0.f, 0.f};
    const _Float16* arow = Sb + (mt * 16 + li) * 72 + 8 * g;
    const _Float16* brow = Vt + (nt * 16 + li) * 72 + 8 * g;
#pragma unroll
    for (int kk = 0; kk < 2; kk++)
      acc = MFMA(*(const f16x8*)(arow + kk * 32), *(const f16x8*)(brow + kk * 32), acc);
#pragma unroll
    for (int r = 0; r < 4; r++)
      SA[(mt * 16 + 4 * g + r) * 228 + (nt * 16 + li)] = acc[r];
  }
  __syncthreads();

  float* ob = out + (size_t)b * 3200;
  for (int t = tid; t < 3200; t += 512) {
    int c = t >> 4, s = t & 15;
    float cv = Cv[s * 226 + c] + convb[c];
    float pool = 0.f;
#pragma unroll
    for (int j = 0; j < 4; j++) {
      int flat = c * 64 + j * 16 + s;
      int l = flat / 200;
      int h = flat - l * 200;
      pool += SA[l * 228 + h];
    }
    ob[t] = cv + 0.25f * pool;
  }
}

// ---- launch -----------------------------------------------------------------
extern "C" void kernel_launch(void* const* d_in, const int* in_sizes, int n_in,
                              void* d_out, int out_size, void* d_ws, size_t ws_size,
                              hipStream_t stream) {
  const float* x  = (const float*)d_in[0];
  const float* Wq = (const float*)d_in[1];
  const float* bq = (const float*)d_in[2];
  const float* Wk = (const float*)d_in[3];
  const float* bk = (const float*)d_in[4];
  const float* Wv = (const float*)d_in[5];
  const float* bv = (const float*)d_in[6];
  const float* cw = (const float*)d_in[7];
  const float* cb = (const float*)d_in[8];

  char* ws = (char*)d_ws;
  _Float16* Wb  = (_Float16*)ws;             // 344064 B
  _Float16* Wcb = (_Float16*)(ws + 344064);  // 458752 B
  float* biasp  = (float*)(ws + 802816);     // 2688 B

  hipLaunchKernelGGL(wcvt, dim3(512), dim3(256), 0, stream,
                     Wq, Wk, Wv, cw, bq, bk, bv, Wb, Wcb, biasp);

  const size_t QKV_BASE = 805888ull;
  const size_t QKV_ONE  = 117440512ull;           // 4096*64*224*2
  const size_t NEED = QKV_BASE + 3ull * QKV_ONE;  // ~353 MB

  if (ws_size >= NEED) {
    _Float16* Qg  = (_Float16*)(ws + QKV_BASE);
    _Float16* Kg  = (_Float16*)(ws + QKV_BASE + QKV_ONE);
    _Float16* Vtg = (_Float16*)(ws + QKV_BASE + 2 * QKV_ONE);

    hipFuncSetAttribute((const void*)k1_proj_conv,
                        hipFuncAttributeMaxDynamicSharedMemorySize, 67584);
    hipLaunchKernelGGL(k1_proj_conv, dim3(2048), dim3(512), 67584, stream,
                       x, Wb, Wcb, biasp, cb, Qg, Kg, Vtg, (float*)d_out);

    hipFuncSetAttribute((const void*)k3_attn,
                        hipFuncAttributeMaxDynamicSharedMemorySize, K3_LDS);
    hipLaunchKernelGGL(k3_attn, dim3(K3_GRID), dim3(256), K3_LDS, stream,
                       Qg, Kg, Vtg, (float*)d_out);
  } else {
    hipFuncSetAttribute((const void*)fused_fallback,
                        hipFuncAttributeMaxDynamicSharedMemorySize, FB_LDS);
    hipLaunchKernelGGL(fused_fallback, dim3(4096), dim3(512), FB_LDS, stream,
                       x, Wb, Wcb, biasp, cb, (float*)d_out);
  }
}

// Round 9
// 570.904 us; speedup vs baseline: 1.3727x; 1.3727x over previous
//
#include <hip/hip_runtime.h>

typedef _Float16 f16x8 __attribute__((ext_vector_type(8)));
typedef _Float16 f16x4 __attribute__((ext_vector_type(4)));
typedef float f32x4 __attribute__((ext_vector_type(4)));

static __device__ __forceinline__ f32x4 MFMA(f16x8 a, f16x8 b, f32x4 c) {
  return __builtin_amdgcn_mfma_f32_16x16x32_f16(a, b, c, 0, 0, 0);
}

// ---- weight conversion pre-kernel ------------------------------------------
// ws layout:
//   Wb   : 3 x [224][256] f16  (Wq,Wk,Wv; rows >=200 zero)      @ 0       (344064 B)
//   Wcb  : [224][1024] f16     (conv_w flat; rows >=200 zero)   @ 344064  (458752 B)
//   biasp: 3 x [224] f32       (bq,bk,bv padded w/ zeros)       @ 802816  (2688 B)
//   Qg   : [4096][64][224] f16                                  @ 805888
//   Kg   : [4096][64][224] f16                                  @ 805888+117440512
//   Vtg  : [4096][224][64] f16                                  @ 805888+234881024
__global__ void wcvt(const float* __restrict__ Wq, const float* __restrict__ Wk,
                     const float* __restrict__ Wv, const float* __restrict__ cw,
                     const float* __restrict__ bq, const float* __restrict__ bk,
                     const float* __restrict__ bv,
                     _Float16* __restrict__ Wb,
                     _Float16* __restrict__ Wcb,
                     float* __restrict__ biasp) {
  int gt = blockIdx.x * blockDim.x + threadIdx.x;
  int gs = gridDim.x * blockDim.x;
  const int WN = 224 * 256;
  for (int i = gt; i < WN; i += gs) {
    int n = i >> 8;
    Wb[i]          = (n < 200) ? (_Float16)Wq[i] : (_Float16)0.f;
    Wb[WN + i]     = (n < 200) ? (_Float16)Wk[i] : (_Float16)0.f;
    Wb[2 * WN + i] = (n < 200) ? (_Float16)Wv[i] : (_Float16)0.f;
  }
  for (int i = gt; i < 224 * 1024; i += gs) {
    int o = i >> 10;
    Wcb[i] = (o < 200) ? (_Float16)cw[i] : (_Float16)0.f;
  }
  for (int i = gt; i < 224; i += gs) {
    biasp[i]       = (i < 200) ? bq[i] : 0.f;
    biasp[224 + i] = (i < 200) ? bk[i] : 0.f;
    biasp[448 + i] = (i < 200) ? bv[i] : 0.f;
  }
}

// ---- K1 v2: projections + conv, 2 batches per block, 2 blocks/CU ------------
// (round-6 known-good, ~250us)
__global__ __launch_bounds__(512, 4) void k1_proj_conv(
    const float* __restrict__ x, const _Float16* __restrict__ Wb,
    const _Float16* __restrict__ Wcb, const float* __restrict__ biasp,
    const float* __restrict__ convb,
    _Float16* __restrict__ Qg, _Float16* __restrict__ Kg,
    _Float16* __restrict__ Vtg, float* __restrict__ out) {
  extern __shared__ char smem[];
  _Float16* Xl = (_Float16*)smem;  // 2 x [64][264]
  const int tid = threadIdx.x, lane = tid & 63, wave = tid >> 6;
  const int li = lane & 15, g = lane >> 4;
  const int b0 = blockIdx.x * 2;

  const float* xb = x + (size_t)b0 * 16384;
#pragma unroll
  for (int j = 0; j < 16; j++) {
    int f = tid + 512 * j;
    float4 v = ((const float4*)xb)[f];
    int bt = f >> 12, rem = f & 4095, l = rem >> 6, c4 = rem & 63;
    f16x4 h;
    h.x = (_Float16)v.x; h.y = (_Float16)v.y;
    h.z = (_Float16)v.z; h.w = (_Float16)v.w;
    *(f16x4*)(Xl + bt * 16896 + l * 264 + c4 * 4) = h;
  }
  __syncthreads();

#pragma unroll 1
  for (int i = 0; i < 7; i++) {
    int u = wave + 8 * i;
    if (u < 28) {
      // ---- Q/K unit, swapped operands: D[n][l] ----
      int p = u / 14, nt = u % 14;
      const _Float16* wrow = Wb + p * 57344 + (nt * 16 + li) * 256 + 8 * g;
      f32x4 acc[2][4] = {};
#pragma unroll
      for (int kk = 0; kk < 8; kk++) {
        f16x8 aw = *(const f16x8*)(wrow + 32 * kk);
#pragma unroll
        for (int bt = 0; bt < 2; bt++)
#pragma unroll
          for (int mt = 0; mt < 4; mt++) {
            f16x8 bx = *(const f16x8*)(Xl + bt * 16896 + (mt * 16 + li) * 264 + 32 * kk + 8 * g);
            acc[bt][mt] = MFMA(aw, bx, acc[bt][mt]);
          }
      }
      float4 b4 = *(const float4*)(biasp + p * 224 + nt * 16 + 4 * g);
      _Float16* dst0 = (p == 0) ? Qg : Kg;
#pragma unroll
      for (int bt = 0; bt < 2; bt++) {
        _Float16* db = dst0 + (size_t)(b0 + bt) * 14336;
#pragma unroll
        for (int mt = 0; mt < 4; mt++) {
          f16x4 hv;
          {
            float v0 = acc[bt][mt][0] + b4.x; hv[0] = (_Float16)(v0 > 0.f ? v0 : 0.f);
            float v1 = acc[bt][mt][1] + b4.y; hv[1] = (_Float16)(v1 > 0.f ? v1 : 0.f);
            float v2 = acc[bt][mt][2] + b4.z; hv[2] = (_Float16)(v2 > 0.f ? v2 : 0.f);
            float v3 = acc[bt][mt][3] + b4.w; hv[3] = (_Float16)(v3 > 0.f ? v3 : 0.f);
          }
          *(f16x4*)(db + (mt * 16 + li) * 224 + nt * 16 + 4 * g) = hv;
        }
      }
    } else if (u < 42) {
      // ---- V unit, normal operands: D[l][h]; store transposed [h][l] ----
      int nt = u - 28;
      const _Float16* wrow = Wb + 2 * 57344 + (nt * 16 + li) * 256 + 8 * g;
      f32x4 acc[2][4] = {};
#pragma unroll
      for (int kk = 0; kk < 8; kk++) {
        f16x8 bw = *(const f16x8*)(wrow + 32 * kk);
#pragma unroll
        for (int bt = 0; bt < 2; bt++)
#pragma unroll
          for (int mt = 0; mt < 4; mt++) {
            f16x8 ax = *(const f16x8*)(Xl + bt * 16896 + (mt * 16 + li) * 264 + 32 * kk + 8 * g);
            acc[bt][mt] = MFMA(ax, bw, acc[bt][mt]);
          }
      }
      float bias = biasp[448 + nt * 16 + li];
#pragma unroll
      for (int bt = 0; bt < 2; bt++) {
        _Float16* db = Vtg + (size_t)(b0 + bt) * 14336;
#pragma unroll
        for (int mt = 0; mt < 4; mt++) {
          f16x4 hv;
#pragma unroll
          for (int r = 0; r < 4; r++) {
            float v = acc[bt][mt][r] + bias;
            hv[r] = (_Float16)(v > 0.f ? v : 0.f);
          }
          *(f16x4*)(db + (nt * 16 + li) * 64 + mt * 16 + 4 * g) = hv;
        }
      }
    } else {
      // ---- conv unit ----
      int nt = u - 42, o = nt * 16 + li;
      const _Float16* wrow = Wcb + o * 1024 + 8 * g;
      f32x4 acc[2] = {};
#pragma unroll 4
      for (int kk = 0; kk < 32; kk++) {
        f16x8 bf = *(const f16x8*)(wrow + 32 * kk);
        int i1 = kk * 8 + 2 * g;
        int i2 = i1 + 1;
#pragma unroll
        for (int bt = 0; bt < 2; bt++) {
          const _Float16* xt = Xl + bt * 16896;
          union { f16x4 h[2]; f16x8 v; } af;
          af.h[0] = *(const f16x4*)(xt + (i1 >> 2) * 264 + ((i1 & 3) << 6) + 4 * li);
          af.h[1] = *(const f16x4*)(xt + (i2 >> 2) * 264 + ((i2 & 3) << 6) + 4 * li);
          acc[bt] = MFMA(af.v, bf, acc[bt]);
        }
      }
      if (o < 200) {
        float cb = convb[o];
#pragma unroll
        for (int bt = 0; bt < 2; bt++) {
          float4 vo;
          vo.x = acc[bt][0] + cb; vo.y = acc[bt][1] + cb;
          vo.z = acc[bt][2] + cb; vo.w = acc[bt][3] + cb;
          *(float4*)(out + (size_t)(b0 + bt) * 3200 + o * 16 + 4 * g) = vo;
        }
      }
    }
  }
}

// ---- K3 v4: LDS-light attention — all MFMA operands from global/L2 ----------
// LDS map (bytes):
//   Sb  [64][72]  f16 @ 0      (9216)   (normalized P)
//   part[2][4][64] f32 @ 9216  (2048)   (per-wave col max/sum partials)
//   Po  [200][17] f32 @ 11264  (13600)  (pooled accumulator)
// total 24864 -> 6 blocks/CU (24 waves, 75% occupancy). 3 barriers.
#define K3_LDS 24864
__global__ __launch_bounds__(256, 6) void k3_attn(
    const _Float16* __restrict__ Qg, const _Float16* __restrict__ Kg,
    const _Float16* __restrict__ Vtg, float* __restrict__ out) {
  extern __shared__ char smem[];
  _Float16* Sb   = (_Float16*)smem;            // [64][72]
  float*    part = (float*)(smem + 9216);      // [2][4][64]
  float*    Po   = (float*)(smem + 11264);     // [200][17]

  const int b = blockIdx.x;
  const int tid = threadIdx.x, lane = tid & 63, wave = tid >> 6;
  const int li = lane & 15, g = lane >> 4;
  const size_t bb = (size_t)b * 14336;
  const int mt = wave;

  // zero Po (visible at BAR1)
  for (int i = tid; i < 3400; i += 256) Po[i] = 0.f;

  // Q fragments for this wave's row-tile (global, L2/L3)
  f16x8 qreg[7];
#pragma unroll
  for (int kk = 0; kk < 7; kk++)
    qreg[kk] = *(const f16x8*)(Qg + bb + (mt * 16 + li) * 224 + kk * 32 + 8 * g);

  // scores: B-fragments straight from global K (16 rows x 64B lines, L2-served)
  f32x4 sacc[4] = {};
#pragma unroll
  for (int kk = 0; kk < 7; kk++) {
#pragma unroll
    for (int nt = 0; nt < 4; nt++) {
      f16x8 kb = *(const f16x8*)(Kg + bb + (nt * 16 + li) * 224 + kk * 32 + 8 * g);
      sacc[nt] = MFMA(qreg[kk], kb, sacc[nt]);
    }
  }

  // per-wave column partials (softmax over l = rows): in-lane r, shfl over g
  float mw[4];
#pragma unroll
  for (int nt = 0; nt < 4; nt++) {
    float m0 = fmaxf(fmaxf(sacc[nt][0], sacc[nt][1]),
                     fmaxf(sacc[nt][2], sacc[nt][3]));
    m0 = fmaxf(m0, __shfl_xor(m0, 16));
    m0 = fmaxf(m0, __shfl_xor(m0, 32));
    mw[nt] = m0;
#pragma unroll
    for (int r = 0; r < 4; r++) sacc[nt][r] = __expf(sacc[nt][r] - m0);
    float s0 = sacc[nt][0] + sacc[nt][1] + sacc[nt][2] + sacc[nt][3];
    s0 += __shfl_xor(s0, 16);
    s0 += __shfl_xor(s0, 32);
    if (g == 0) {
      part[wave * 64 + nt * 16 + li] = m0;
      part[256 + wave * 64 + nt * 16 + li] = s0;
    }
  }
  __syncthreads();  // BAR1: part + Po-zero visible

  // merge cross-wave partials; normalize into Sb
#pragma unroll
  for (int nt = 0; nt < 4; nt++) {
    int col = nt * 16 + li;
    float m0 = part[col], m1 = part[64 + col];
    float m2 = part[128 + col], m3 = part[192 + col];
    float M = fmaxf(fmaxf(m0, m1), fmaxf(m2, m3));
    float S = part[256 + col] * __expf(m0 - M) +
              part[320 + col] * __expf(m1 - M) +
              part[384 + col] * __expf(m2 - M) +
              part[448 + col] * __expf(m3 - M);
    float scale = __expf(mw[nt] - M) / S;
#pragma unroll
    for (int r = 0; r < 4; r++)
      Sb[(mt * 16 + 4 * g + r) * 72 + col] = (_Float16)(sacc[nt][r] * scale);
  }
  __syncthreads();  // BAR2: Sb visible

  // PV: A = P frags (LDS), B = V^T frags (global); pooled atomics into Po
  f16x8 pa[2][4];
#pragma unroll
  for (int kk = 0; kk < 2; kk++)
#pragma unroll
    for (int m2 = 0; m2 < 4; m2++)
      pa[kk][m2] = *(const f16x8*)(Sb + (m2 * 16 + li) * 72 + kk * 32 + 8 * g);

#pragma unroll 1
  for (int ntl = wave; ntl < 14; ntl += 4) {
    int h = ntl * 16 + li;
    f16x8 vb[2];
#pragma unroll
    for (int kk = 0; kk < 2; kk++)
      vb[kk] = *(const f16x8*)(Vtg + bb + h * 64 + kk * 32 + 8 * g);
    f32x4 pacc[4] = {};
#pragma unroll
    for (int kk = 0; kk < 2; kk++)
#pragma unroll
      for (int m2 = 0; m2 < 4; m2++)
        pacc[m2] = MFMA(pa[kk][m2], vb[kk], pacc[m2]);
    if (h < 200) {
#pragma unroll
      for (int m2 = 0; m2 < 4; m2++)
#pragma unroll
        for (int r = 0; r < 4; r++) {
          int l = m2 * 16 + 4 * g + r;
          int f = l * 200 + h;
          atomicAdd(&Po[(f >> 6) * 17 + (f & 15)], 0.25f * pacc[m2][r]);
        }
    }
  }
  __syncthreads();  // BAR3: Po complete

  float* ob = out + (size_t)b * 3200;
  for (int t = tid; t < 3200; t += 256) {
    int c = t >> 4;
    ob[t] += Po[c * 17 + (t & 15)];
  }
}

// ---- fallback: round-2 fused kernel (known-good 533us), used if ws too small
#define FB_LDS 151296
__global__ __launch_bounds__(512, 2) void fused_fallback(
    const float* __restrict__ x, const _Float16* __restrict__ Wb,
    const _Float16* __restrict__ Wcb, const float* __restrict__ biasp,
    const float* __restrict__ convb, float* __restrict__ out) {
  extern __shared__ char smem[];
  _Float16* Xl = (_Float16*)smem;            // [64][264]
  _Float16* Qs = (_Float16*)(smem + 33792);  // [64][232]
  _Float16* Ks = (_Float16*)(smem + 63488);  // [64][232]
  _Float16* Vt = (_Float16*)(smem + 93184);  // [224][72]
  float* Sf    = (float*)(smem + 125440);    // [64][65]
  _Float16* Sb = (_Float16*)(smem + 142080); // [64][72]
  float* SA    = (float*)(smem + 33792);     // [64][228]
  float* Cv    = (float*)(smem + 125440);    // [16][226]

  const int b = blockIdx.x;
  const int tid = threadIdx.x;
  const int lane = tid & 63;
  const int wave = tid >> 6;
  const int li = lane & 15;
  const int g = lane >> 4;

  const float* xb = x + (size_t)b * 16384;
  for (int i = tid; i < 4096; i += 512) {
    float4 v = ((const float4*)xb)[i];
    int e = i * 4;
    int l = e >> 8, d = e & 255;
    f16x4 h;
    h.x = (_Float16)v.x; h.y = (_Float16)v.y;
    h.z = (_Float16)v.z; h.w = (_Float16)v.w;
    *(f16x4*)(Xl + l * 264 + d) = h;
  }
  __syncthreads();

  for (int u = wave; u < 42; u += 8) {
    int p = u / 14, nt = u % 14;
    int n = nt * 16 + li;
    const _Float16* wrow = Wb + p * 57344 + n * 256 + 8 * g;
    f16x8 bfr[8];
#pragma unroll
    for (int kk = 0; kk < 8; kk++) bfr[kk] = *(const f16x8*)(wrow + kk * 32);
    float bias = biasp[p * 224 + n];
    for (int m = 0; m < 4; m++) {
      f32x4 acc = {0.f, 0.f, 0.f, 0.f};
      const _Float16* arow = Xl + (m * 16 + li) * 264 + 8 * g;
#pragma unroll
      for (int kk = 0; kk < 8; kk++) acc = MFMA(*(const f16x8*)(arow + kk * 32), bfr[kk], acc);
#pragma unroll
      for (int r = 0; r < 4; r++) {
        int row = m * 16 + 4 * g + r;
        float v = acc[r] + bias;
        v = v > 0.f ? v : 0.f;
        _Float16 hv = (_Float16)v;
        if (p == 0) Qs[row * 232 + n] = hv;
        else if (p == 1) Ks[row * 232 + n] = hv;
        else Vt[n * 72 + row] = hv;
      }
    }
  }
  __syncthreads();

  for (int t = wave * 2; t < wave * 2 + 2; t++) {
    int mt = t >> 2, nt = t & 3;
    f32x4 acc = {0.f, 0.f, 0.f, 0.f};
    const _Float16* qrow = Qs + (mt * 16 + li) * 232 + 8 * g;
    const _Float16* krow = Ks + (nt * 16 + li) * 232 + 8 * g;
#pragma unroll
    for (int kk = 0; kk < 7; kk++)
      acc = MFMA(*(const f16x8*)(qrow + kk * 32), *(const f16x8*)(krow + kk * 32), acc);
#pragma unroll
    for (int r = 0; r < 4; r++)
      Sf[(mt * 16 + 4 * g + r) * 65 + nt * 16 + li] = acc[r];
  }
  __syncthreads();

  {
    int m = tid >> 3, r = tid & 7;
    float vals[8];
    float mx = -1e30f;
#pragma unroll
    for (int i = 0; i < 8; i++) {
      float v = Sf[(r + 8 * i) * 65 + m];
      vals[i] = v;
      mx = fmaxf(mx, v);
    }
    mx = fmaxf(mx, __shfl_xor(mx, 1));
    mx = fmaxf(mx, __shfl_xor(mx, 2));
    mx = fmaxf(mx, __shfl_xor(mx, 4));
    float s = 0.f;
#pragma unroll
    for (int i = 0; i < 8; i++) { vals[i] = __expf(vals[i] - mx); s += vals[i]; }
    s += __shfl_xor(s, 1);
    s += __shfl_xor(s, 2);
    s += __shfl_xor(s, 4);
    float inv = 1.0f / s;
#pragma unroll
    for (int i = 0; i < 8; i++)
      Sb[(r + 8 * i) * 72 + m] = (_Float16)(vals[i] * inv);
  }
  __syncthreads();

  for (int nt = wave; nt < 14; nt += 8) {
    int o = nt * 16 + li;
    const _Float16* wrow = Wcb + o * 1024 + 8 * g;
    f32x4 acc = {0.f, 0.f, 0.f, 0.f};
#pragma unroll 4
    for (int kk = 0; kk < 32; kk++) {
      int i1 = kk * 8 + 2 * g;
      int i2 = i1 + 1;
      union { f16x4 h[2]; f16x8 v; } af;
      af.h[0] = *(const f16x4*)(Xl + (i1 >> 2) * 264 + ((i1 & 3) << 6) + 4 * li);
      af.h[1] = *(const f16x4*)(Xl + (i2 >> 2) * 264 + ((i2 & 3) << 6) + 4 * li);
      acc = MFMA(af.v, *(const f16x8*)(wrow + 32 * kk), acc);
    }
#pragma unroll
    for (int r = 0; r < 4; r++) Cv[(4 * g + r) * 226 + o] = acc[r];
  }

  for (int t = wave; t < 56; t += 8) {
    int mt = t / 14, nt = t % 14;
    f32x4 acc = {0.f, 0.f, 0.f, 0.f};
    const _Float16* arow = Sb + (mt * 16 + li) * 72 + 8 * g;
    const _Float16* brow = Vt + (nt * 16 + li) * 72 + 8 * g;
#pragma unroll
    for (int kk = 0; kk < 2; kk++)
      acc = MFMA(*(const f16x8*)(arow + kk * 32), *(const f16x8*)(brow + kk * 32), acc);
#pragma unroll
    for (int r = 0; r < 4; r++)
      SA[(mt * 16 + 4 * g + r) * 228 + (nt * 16 + li)] = acc[r];
  }
  __syncthreads();

  float* ob = out + (size_t)b * 3200;
  for (int t = tid; t < 3200; t += 512) {
    int c = t >> 4, s = t & 15;
    float cv = Cv[s * 226 + c] + convb[c];
    float pool = 0.f;
#pragma unroll
    for (int j = 0; j < 4; j++) {
      int flat = c * 64 + j * 16 + s;
      int l = flat / 200;
      int h = flat - l * 200;
      pool += SA[l * 228 + h];
    }
    ob[t] = cv + 0.25f * pool;
  }
}

// ---- launch -----------------------------------------------------------------
extern "C" void kernel_launch(void* const* d_in, const int* in_sizes, int n_in,
                              void* d_out, int out_size, void* d_ws, size_t ws_size,
                              hipStream_t stream) {
  const float* x  = (const float*)d_in[0];
  const float* Wq = (const float*)d_in[1];
  const float* bq = (const float*)d_in[2];
  const float* Wk = (const float*)d_in[3];
  const float* bk = (const float*)d_in[4];
  const float* Wv = (const float*)d_in[5];
  const float* bv = (const float*)d_in[6];
  const float* cw = (const float*)d_in[7];
  const float* cb = (const float*)d_in[8];

  char* ws = (char*)d_ws;
  _Float16* Wb  = (_Float16*)ws;             // 344064 B
  _Float16* Wcb = (_Float16*)(ws + 344064);  // 458752 B
  float* biasp  = (float*)(ws + 802816);     // 2688 B

  hipLaunchKernelGGL(wcvt, dim3(512), dim3(256), 0, stream,
                     Wq, Wk, Wv, cw, bq, bk, bv, Wb, Wcb, biasp);

  const size_t QKV_BASE = 805888ull;
  const size_t QKV_ONE  = 117440512ull;           // 4096*64*224*2
  const size_t NEED = QKV_BASE + 3ull * QKV_ONE;  // ~353 MB

  if (ws_size >= NEED) {
    _Float16* Qg  = (_Float16*)(ws + QKV_BASE);
    _Float16* Kg  = (_Float16*)(ws + QKV_BASE + QKV_ONE);
    _Float16* Vtg = (_Float16*)(ws + QKV_BASE + 2 * QKV_ONE);

    hipFuncSetAttribute((const void*)k1_proj_conv,
                        hipFuncAttributeMaxDynamicSharedMemorySize, 67584);
    hipLaunchKernelGGL(k1_proj_conv, dim3(2048), dim3(512), 67584, stream,
                       x, Wb, Wcb, biasp, cb, Qg, Kg, Vtg, (float*)d_out);

    hipFuncSetAttribute((const void*)k3_attn,
                        hipFuncAttributeMaxDynamicSharedMemorySize, K3_LDS);
    hipLaunchKernelGGL(k3_attn, dim3(4096), dim3(256), K3_LDS, stream,
                       Qg, Kg, Vtg, (float*)d_out);
  } else {
    hipFuncSetAttribute((const void*)fused_fallback,
                        hipFuncAttributeMaxDynamicSharedMemorySize, FB_LDS);
    hipLaunchKernelGGL(fused_fallback, dim3(4096), dim3(512), FB_LDS, stream,
                       x, Wb, Wcb, biasp, cb, (float*)d_out);
  }
}